// Round 10
// baseline (1524.923 us; speedup 1.0000x reference)
//
#include <hip/hip_runtime.h>
#include <cfloat>

#define BB 8
#define NN 1024
#define CC 256
#define KK 4096
#define SN 11
#define BNC (BB*NN*CC)
#define RMAX 8192
#define NBLK 512

typedef __attribute__((ext_vector_type(8))) _Float16 half8;
typedef __attribute__((ext_vector_type(4))) float f32x4;

__device__ __forceinline__ void split2(float v, ushort& h, ushort& l) {
    union { _Float16 f; ushort u; } a, b;
    a.f = (_Float16)v;
    b.f = (_Float16)(v - (float)a.f);
    h = a.u; l = b.u;
}

// Software grid barrier: monotone counter. Increment = relaxed RMW (once per
// block); poll = relaxed agent-scope LOAD (no RMW -> no L2 serialization),
// with s_sleep backoff. Fences give release/acquire. Safe: grid(512) == exact
// co-resident capacity (2 blocks/CU by 67.5KB LDS).
__device__ __forceinline__ void gbar(unsigned* cnt, unsigned target) {
    __syncthreads();                    // all waves' stores issued (vmcnt drain)
    if (threadIdx.x == 0) {
        __threadfence();                // release: writes visible at agent scope
        __hip_atomic_fetch_add(cnt, 1u, __ATOMIC_RELAXED, __HIP_MEMORY_SCOPE_AGENT);
        while (__hip_atomic_load(cnt, __ATOMIC_RELAXED, __HIP_MEMORY_SCOPE_AGENT) < target)
            __builtin_amdgcn_s_sleep(16);
        __threadfence();                // acquire: invalidate stale caches
    }
    __syncthreads();
}

// LDS phase union (max member = MFMA tiles: 64KB + 2KB argmin staging)
struct SMm { ushort tiles[4096 * 8]; float wv[2][128]; int wi[2][128]; };
struct SMs { float qs[32][CC]; float es[64][33]; };
struct SMe { float bs[16][CC]; float wpart[16][4]; };
struct SMu { float4 rlds[16][64]; int sel[20]; float wred[4]; };
struct SMr { float red[256]; };
union SMem { SMm m; SMs s; SMe e; SMu u; SMr r; };

// ---------------------------------------------------------------------------
__global__ void transpose_pw(const float* __restrict__ pw, float* __restrict__ pwT) {
    int j = blockIdx.x;
    int c = threadIdx.x;
    pwT[j * CC + c] = pw[c * CC + j];
}

// ---------------------------------------------------------------------------
// ONE persistent kernel: embed||init -> 11x {dist -> bar -> update -> bar}
// -> final reduce. All arithmetic orders identical to the round-7 kernels.
__global__ __launch_bounds__(256, 2) void mega(
    const float* __restrict__ f, const float* __restrict__ base,
    const float* __restrict__ pwT, const float* __restrict__ pb,
    float* __restrict__ out,
    float* __restrict__ emb, float* __restrict__ esq,
    float* __restrict__ parts, float* __restrict__ pval, int* __restrict__ pidx,
    float* __restrict__ p16, float* __restrict__ p16u, float* __restrict__ qf,
    float* __restrict__ resid,
    ushort* __restrict__ eh, ushort* __restrict__ el,
    ushort* __restrict__ qh, ushort* __restrict__ ql,
    unsigned* __restrict__ cnt) {
    __shared__ SMem sm;
    const int blk = blockIdx.x;
    const int t = threadIdx.x;
    const int w = t >> 6, lane = t & 63;
    unsigned bph = 0;

    // ======== phase 0: embed (blocks 0-255)  ||  init_pool16 (blocks 256-511)
    if (blk < 256) {
        int k0 = blk * 16;
        for (int i = t; i < 16 * CC; i += 256) sm.e.bs[i >> 8][i & 255] = base[k0 * CC + i];
        __syncthreads();
        float acc[16];
#pragma unroll
        for (int m = 0; m < 16; ++m) acc[m] = 0.f;
        for (int j = 0; j < CC; ++j) {
            float wgt = pwT[j * CC + t];
#pragma unroll
            for (int m = 0; m < 16; ++m) acc[m] += sm.e.bs[m][j] * wgt;
        }
        float bias = pb[t];
#pragma unroll
        for (int m = 0; m < 16; ++m) {
            float v = acc[m] + bias;
            int o = (k0 + m) * CC + t;
            emb[o] = v;
            ushort h, l;
            split2(64.f * v, h, l);
            eh[o] = h; el[o] = l;
            float sq = v * v;
#pragma unroll
            for (int d = 1; d < 64; d <<= 1) sq += __shfl_xor(sq, d);
            if (lane == 0) sm.e.wpart[m][w] = sq;
        }
        __syncthreads();
        if (t < 16) esq[k0 + t] = sm.e.wpart[t][0] + sm.e.wpart[t][1] +
                                  sm.e.wpart[t][2] + sm.e.wpart[t][3];
    } else {
        for (int bb = blk - 256; bb < 512; bb += 256) {
            int c4 = t & 63;
            const float4* src = (const float4*)(f + (size_t)bb * 16 * CC) + c4;
            float4 s = make_float4(0.f, 0.f, 0.f, 0.f);
#pragma unroll
            for (int j = 0; j < 16; ++j) {
                float4 v = src[(size_t)j * 64];
                s.x += v.x; s.y += v.y; s.z += v.z; s.w += v.w;
            }
            ((float4*)(p16 + (size_t)bb * CC))[c4] = s;
        }
    }
    gbar(cnt, (++bph) * NBLK);

    // ======== scale loop
    for (int sc = 0; sc < SN; ++sc) {
        int pn = 1 << sc;
        int R = BB * pn;
        int ks;
        if (pn <= 64) {
            // ---- dist_small phase (fused pooling), grid-stride over 64 x rch
            ks = 64;
            const float* src;
            float inv;
            int g16;
            if (pn == 64)      { src = qf;   g16 = 1;       inv = 1.f; }
            else if (pn == 1)  { src = p16;  g16 = 64;      inv = 1.f / 1024.f; }
            else               { src = p16u; g16 = 64 / pn; inv = 1.f / (16.f * (64 / pn)); }
            int rch = (R + 31) / 32;
            int ntile = 64 * rch;
            for (int tile = blk; tile < ntile; tile += NBLK) {
                __syncthreads();  // protect qs/es reuse across tiles
                int kbx = tile & 63, rc = tile >> 6;
                int k0 = kbx * 64;
                int r0c = rc * 32;
                int ws = w, j = lane;
                {
                    int row = t >> 3;
                    int f4b = (t & 7) * 8;
                    int gr = r0c + row;
                    float4 a4[8];
#pragma unroll
                    for (int ii = 0; ii < 8; ++ii) a4[ii] = make_float4(0.f, 0.f, 0.f, 0.f);
                    if (gr < R) {
                        int b = gr / pn, p = gr - b * pn;
                        const float4* sp = (const float4*)(src + ((size_t)b * 64 + (size_t)p * g16) * CC) + f4b;
                        for (int i = 0; i < g16; ++i) {
#pragma unroll
                            for (int ii = 0; ii < 8; ++ii) {
                                float4 v = sp[ii];
                                a4[ii].x += v.x; a4[ii].y += v.y; a4[ii].z += v.z; a4[ii].w += v.w;
                            }
                            sp += 64;
                        }
                    }
#pragma unroll
                    for (int ii = 0; ii < 8; ++ii) {
                        a4[ii].x *= inv; a4[ii].y *= inv; a4[ii].z *= inv; a4[ii].w *= inv;
                        *(float4*)&sm.s.qs[row][(f4b + ii) * 4] = a4[ii];
                    }
                }
                float acc[8];
#pragma unroll
                for (int ri = 0; ri < 8; ++ri) acc[ri] = 0.f;
                for (int ck = 0; ck < 8; ++ck) {
                    __syncthreads();
                    {
                        int code = t >> 2, cb = (t & 3) * 8;
                        float4 v0 = *(const float4*)&emb[(size_t)(k0 + code) * CC + ck * 32 + cb];
                        float4 v1 = *(const float4*)&emb[(size_t)(k0 + code) * CC + ck * 32 + cb + 4];
                        sm.s.es[code][cb + 0] = v0.x; sm.s.es[code][cb + 1] = v0.y;
                        sm.s.es[code][cb + 2] = v0.z; sm.s.es[code][cb + 3] = v0.w;
                        sm.s.es[code][cb + 4] = v1.x; sm.s.es[code][cb + 5] = v1.y;
                        sm.s.es[code][cb + 6] = v1.z; sm.s.es[code][cb + 7] = v1.w;
                    }
                    __syncthreads();
                    for (int c = 0; c < 32; ++c) {
                        float ev = sm.s.es[j][c];
#pragma unroll
                        for (int ri = 0; ri < 8; ++ri)
                            acc[ri] += sm.s.qs[ws + 4 * ri][ck * 32 + c] * ev;
                    }
                }
                float esv = esq[k0 + j];
#pragma unroll
                for (int ri = 0; ri < 8; ++ri) {
                    int r = r0c + ws + 4 * ri;
                    if (r >= R) continue;
                    float v = esv - 2.f * acc[ri];
                    int bi = k0 + j;
#pragma unroll
                    for (int d = 1; d < 64; d <<= 1) {
                        float ov = __shfl_xor(v, d);
                        int oi = __shfl_xor(bi, d);
                        if (ov < v || (ov == v && oi < bi)) { v = ov; bi = oi; }
                    }
                    if (j == 0) {
                        pval[(size_t)r * 64 + kbx] = v;
                        pidx[(size_t)r * 64 + kbx] = bi;
                    }
                }
            }
        } else {
            // ---- dist_mfma phase, grid-stride over rb x 32 tiles
            ks = 32;
            int rb = R >> 7;
            int ntile = rb << 5;
            for (int tile = blk; tile < ntile; tile += NBLK) {
                int rblk = tile & (rb - 1);
                int kb = tile / rb;
                int l15 = lane & 15, hi = lane >> 4;
                int wr = w >> 1, wc = w & 1;
                int r0 = rblk * 128;
                int k0 = kb * 128;
                f32x4 acc[4][4];
#pragma unroll
                for (int mi = 0; mi < 4; ++mi)
#pragma unroll
                    for (int ni = 0; ni < 4; ++ni) acc[mi][ni] = (f32x4){0.f, 0.f, 0.f, 0.f};

                for (int ck = 0; ck < 4; ++ck) {
                    __syncthreads();
#pragma unroll
                    for (int it = 0; it < 16; ++it) {
                        int s = it * 256 + t;
                        const ushort* g;
                        if (s < 2048) {
                            int a = s >> 10;
                            int rem = s & 1023;
                            int row = rem >> 3, sr = rem & 7;
                            int c = (ck << 6) + ((sr ^ (row & 7)) << 3);
                            g = (a ? ql : qh) + (size_t)(r0 + row) * CC + c;
                        } else {
                            int s2 = s - 2048;
                            int b = s2 >> 10;
                            int rem = s2 & 1023;
                            int kcol = rem >> 3, sr = rem & 7;
                            int c = (ck << 6) + ((sr ^ (kcol & 7)) << 3);
                            g = (b ? el : eh) + (size_t)(k0 + kcol) * CC + c;
                        }
                        ushort* lb = &sm.m.tiles[(size_t)(it * 256 + (w << 6)) * 8];
                        __builtin_amdgcn_global_load_lds(
                            (const __attribute__((address_space(1))) unsigned int*)g,
                            (__attribute__((address_space(3))) unsigned int*)lb, 16, 0, 0);
                    }
                    __syncthreads();
#pragma unroll
                    for (int kk = 0; kk < 2; ++kk) {
                        int cs = (kk << 2) + hi;
                        half8 bf0[4], bf1[4], af[4];
#pragma unroll
                        for (int ni = 0; ni < 4; ++ni) {
                            int kcol = (wc << 6) + (ni << 4) + l15;
                            int sb = 2048 + (kcol << 3) + (cs ^ (kcol & 7));
                            bf0[ni] = *(const half8*)&sm.m.tiles[sb * 8];
                            bf1[ni] = *(const half8*)&sm.m.tiles[(sb + 1024) * 8];
                        }
#pragma unroll
                        for (int mi = 0; mi < 4; ++mi) {
                            int row = (wr << 6) + (mi << 4) + l15;
                            af[mi] = *(const half8*)&sm.m.tiles[((row << 3) + (cs ^ (row & 7))) * 8];
                        }
#pragma unroll
                        for (int mi = 0; mi < 4; ++mi)
#pragma unroll
                            for (int ni = 0; ni < 4; ++ni)
                                acc[mi][ni] = __builtin_amdgcn_mfma_f32_16x16x32_f16(af[mi], bf0[ni], acc[mi][ni], 0, 0, 0);
#pragma unroll
                        for (int mi = 0; mi < 4; ++mi)
#pragma unroll
                            for (int ni = 0; ni < 4; ++ni)
                                acc[mi][ni] = __builtin_amdgcn_mfma_f32_16x16x32_f16(af[mi], bf1[ni], acc[mi][ni], 0, 0, 0);
#pragma unroll
                        for (int mi = 0; mi < 4; ++mi) {
                            int row = (wr << 6) + (mi << 4) + l15;
                            af[mi] = *(const half8*)&sm.m.tiles[(1024 + (row << 3) + (cs ^ (row & 7))) * 8];
                        }
#pragma unroll
                        for (int mi = 0; mi < 4; ++mi)
#pragma unroll
                            for (int ni = 0; ni < 4; ++ni)
                                acc[mi][ni] = __builtin_amdgcn_mfma_f32_16x16x32_f16(af[mi], bf0[ni], acc[mi][ni], 0, 0, 0);
                    }
                }
                int cbase = k0 + (wc << 6) + l15;
                float es4[4];
#pragma unroll
                for (int ni = 0; ni < 4; ++ni) es4[ni] = 4096.f * esq[cbase + ni * 16];
#pragma unroll
                for (int mi = 0; mi < 4; ++mi) {
#pragma unroll
                    for (int reg = 0; reg < 4; ++reg) {
                        float v = es4[0] - 2.f * acc[mi][0][reg];
                        int i = cbase;
#pragma unroll
                        for (int ni = 1; ni < 4; ++ni) {
                            float v1 = es4[ni] - 2.f * acc[mi][ni][reg];
                            if (v1 < v) { v = v1; i = cbase + ni * 16; }
                        }
#pragma unroll
                        for (int d = 1; d < 16; d <<= 1) {
                            float ov = __shfl_xor(v, d);
                            int oi = __shfl_xor(i, d);
                            if (ov < v || (ov == v && oi < i)) { v = ov; i = oi; }
                        }
                        if (l15 == 0) {
                            int row = (wr << 6) + (mi << 4) + (hi << 2) + reg;
                            sm.m.wv[wc][row] = v;
                            sm.m.wi[wc][row] = i;
                        }
                    }
                }
                __syncthreads();
                if (t < 128) {
                    float v = sm.m.wv[0][t];
                    int i = sm.m.wi[0][t];
                    float ov = sm.m.wv[1][t];
                    int oi = sm.m.wi[1][t];
                    if (ov < v || (ov == v && oi < i)) { v = ov; i = oi; }
                    pval[(size_t)(r0 + t) * 64 + kb] = v;
                    pidx[(size_t)(r0 + t) * 64 + kb] = i;
                }
            }
        }
        gbar(cnt, (++bph) * NBLK);

        // ---- update phase: block = (b, n16), 512 blocks exactly
        {
            int pnn = (sc < SN - 1) ? (pn << 1) : 0;
            int gn = pnn ? (NN / pnn) : 0;
            int finalflag = (sc == SN - 1) ? 1 : 0;
            const float* rin = (sc == 0) ? f : resid;
            float* partsw = parts + (size_t)sc * 512;
            int b = blk >> 6, n16 = blk & 63;
            int n0 = n16 * 16;
            const float scale = (float)pn * (1.0f / 1024.0f);
            float s_lo = (n0 + 0.5f) * scale - 0.5f;
            if (s_lo < 0.f) s_lo = 0.f;
            int r_lo = (int)s_lo;
            float s_hi = (n0 + 15.5f) * scale - 0.5f;
            if (s_hi < 0.f) s_hi = 0.f;
            int r_hi = min((int)s_hi + 1, pn - 1);
            int cnt2 = r_hi - r_lo + 1;  // <= 18
            for (int ri = w; ri < cnt2; ri += 4) {
                size_t rowg = (size_t)(b * pn + r_lo + ri) * 64;
                float v = (lane < ks) ? pval[rowg + lane] : FLT_MAX;
                int i = (lane < ks) ? pidx[rowg + lane] : 0x7fffffff;
#pragma unroll
                for (int d = 1; d < 64; d <<= 1) {
                    float ov = __shfl_xor(v, d);
                    int oi = __shfl_xor(i, d);
                    if (ov < v || (ov == v && oi < i)) { v = ov; i = oi; }
                }
                if (lane == 0) sm.u.sel[ri] = i;
            }
            __syncthreads();
            int nsub = t >> 6;
            int c4 = t & 63;
            float sq = 0.f;
#pragma unroll
            for (int jj = 0; jj < 4; ++jj) {
                int j = nsub + 4 * jj;
                int n = n0 + j;
                float s = (n + 0.5f) * scale - 0.5f;
                if (s < 0.f) s = 0.f;
                int i0 = (int)s;
                float wgt = s - (float)i0;
                int i1 = min(i0 + 1, pn - 1);
                int k0 = sm.u.sel[i0 - r_lo];
                int k1 = sm.u.sel[i1 - r_lo];
                float4 e0 = ((const float4*)(emb + (size_t)k0 * CC))[c4];
                float4 e1 = ((const float4*)(emb + (size_t)k1 * CC))[c4];
                float wm = 1.f - wgt;
                float4 h = make_float4(wm * e0.x + wgt * e1.x, wm * e0.y + wgt * e1.y,
                                       wm * e0.z + wgt * e1.z, wm * e0.w + wgt * e1.w);
                size_t o4 = ((size_t)b * NN + n) * 64 + c4;
                float4 rv0 = ((const float4*)rin)[o4];
                float4 rv = make_float4(rv0.x - h.x, rv0.y - h.y, rv0.z - h.z, rv0.w - h.w);
                if (!finalflag) {
                    ((float4*)resid)[o4] = rv;
                } else {
                    float4 fv = ((const float4*)f)[o4];
                    ((float4*)out)[o4] = make_float4(fv.x - rv.x, fv.y - rv.y,
                                                     fv.z - rv.z, fv.w - rv.w);
                }
                sq += rv.x * rv.x + rv.y * rv.y + rv.z * rv.z + rv.w * rv.w;
                sm.u.rlds[j][c4] = rv;
            }
            for (int off = 32; off > 0; off >>= 1) sq += __shfl_down(sq, off);
            if (lane == 0) sm.u.wred[w] = sq;
            __syncthreads();
            if (t == 0) partsw[blk] = sm.u.wred[0] + sm.u.wred[1] + sm.u.wred[2] + sm.u.wred[3];
            if (gn > 0) {
                const float* rl = (const float*)sm.u.rlds;  // [16][256]
                if (gn < 16) {
                    float pr = 0.f;
                    for (int j = 0; j < 16; ++j) {
                        pr += rl[j * CC + t];
                        if ((j & (gn - 1)) == (gn - 1)) {
                            float mean = pr * (1.f / (float)gn);
                            ushort H, L;
                            split2(64.f * mean, H, L);
                            size_t r = (size_t)b * pnn + (size_t)((n0 + j) / gn);
                            qh[r * CC + t] = H;
                            ql[r * CC + t] = L;
                            pr = 0.f;
                        }
                    }
                } else {
                    float pr = 0.f;
                    for (int j = 0; j < 16; ++j) pr += rl[j * CC + t];
                    if (gn == 16) qf[(size_t)blk * CC + t] = pr * (1.f / 16.f);
                    else p16u[(size_t)blk * CC + t] = pr;
                }
            }
        }
        gbar(cnt, (++bph) * NBLK);
    }

    // ======== final loss reduce (block 0 only; all others exit)
    if (blk == 0) {
        float s = 0.f;
        for (int i = t; i < SN * 512; i += 256) s += parts[i];
        sm.r.red[t] = s;
        __syncthreads();
        for (int k = 128; k > 0; k >>= 1) {
            if (t < k) sm.r.red[t] += sm.r.red[t + k];
            __syncthreads();
        }
        if (t == 0) {
            float mean_sum = sm.r.red[0] / (float)BNC;
            out[BNC] = 0.25f * mean_sum / (float)SN;
            out[BNC + 1] = mean_sum / (float)SN;
        }
    }
}

// ---------------------------------------------------------------------------
extern "C" void kernel_launch(void* const* d_in, const int* in_sizes, int n_in,
                              void* d_out, int out_size, void* d_ws, size_t ws_size,
                              hipStream_t stream) {
    const float* f    = (const float*)d_in[0];
    const float* base = (const float*)d_in[1];
    const float* pw   = (const float*)d_in[2];
    const float* pb   = (const float*)d_in[3];
    float* out = (float*)d_out;

    float* emb   = (float*)d_ws;                    // K*C
    float* esq   = emb + (size_t)KK * CC;           // K
    float* pwT   = esq + KK;                        // C*C
    float* parts = pwT + (size_t)CC * CC;           // SN*512
    float* pval  = parts + (size_t)SN * 512;        // RMAX*64
    float* p16   = pval + (size_t)RMAX * 64;        // B*64*C
    float* p16u  = p16 + (size_t)BB * 64 * CC;      // B*64*C
    float* qf    = p16u + (size_t)BB * 64 * CC;     // 512*C
    float* resid = qf + (size_t)512 * CC;           // BNC
    int*   pidx  = (int*)(resid + BNC);             // RMAX*64
    ushort* eh = (ushort*)(pidx + (size_t)RMAX * 64);  // K*C
    ushort* el = eh + (size_t)KK * CC;              // K*C
    ushort* qh = el + (size_t)KK * CC;              // RMAX*C
    ushort* ql = qh + (size_t)RMAX * CC;            // RMAX*C
    unsigned* cnt = (unsigned*)(ql + (size_t)RMAX * CC);  // 1 (barrier counter)

    hipMemsetAsync(cnt, 0, 8, stream);
    transpose_pw<<<CC, CC, 0, stream>>>(pw, pwT);
    mega<<<NBLK, 256, 0, stream>>>(f, base, pwT, pb, out,
                                   emb, esq, parts, pval, pidx,
                                   p16, p16u, qf, resid,
                                   eh, el, qh, ql, cnt);
}

// Round 11
// 776.532 us; speedup vs baseline: 1.9638x; 1.9638x over previous
//
#include <hip/hip_runtime.h>
#include <cfloat>

#define BB 8
#define NN 1024
#define CC 256
#define KK 4096
#define SN 11
#define BNC (BB*NN*CC)
#define RMAX 8192

typedef __attribute__((ext_vector_type(8))) _Float16 half8;
typedef __attribute__((ext_vector_type(4))) float f32x4;

__device__ __forceinline__ void split2(float v, ushort& h, ushort& l) {
    union { _Float16 f; ushort u; } a, b;
    a.f = (_Float16)v;
    b.f = (_Float16)(v - (float)a.f);
    h = a.u; l = b.u;
}

// ---------------------------------------------------------------------------
// merged: blocks 0-255 transpose pw; blocks 256-767 init_pool16
__global__ __launch_bounds__(256) void prep_kernel(const float* __restrict__ pw,
                                                   float* __restrict__ pwT,
                                                   const float* __restrict__ f,
                                                   float* __restrict__ p16) {
    int blk = blockIdx.x;
    int t = threadIdx.x;
    if (blk < 256) {
        pwT[blk * CC + t] = pw[t * CC + blk];
    } else {
        int bb = blk - 256;
        int c4 = t & 63;
        const float4* src = (const float4*)(f + (size_t)bb * 16 * CC) + c4;
        float4 s = make_float4(0.f, 0.f, 0.f, 0.f);
#pragma unroll
        for (int j = 0; j < 16; ++j) {
            float4 v = src[(size_t)j * 64];
            s.x += v.x; s.y += v.y; s.z += v.z; s.w += v.w;
        }
        ((float4*)(p16 + (size_t)bb * CC))[c4] = s;
    }
}

// ---------------------------------------------------------------------------
// embedding = base @ proj_w.T + b ; f32 emb, f16 2-way splits of 64*emb, e_sq
__global__ __launch_bounds__(256) void embed_kernel(
    const float* __restrict__ base, const float* __restrict__ pwT,
    const float* __restrict__ pb, float* __restrict__ emb,
    ushort* __restrict__ eh, ushort* __restrict__ el, float* __restrict__ esq) {
    __shared__ float bs[16][CC];
    __shared__ float wpart[16][4];
    int k0 = blockIdx.x * 16;
    int t = threadIdx.x;
    int w = t >> 6, lane = t & 63;
    for (int i = t; i < 16 * CC; i += 256) bs[i >> 8][i & 255] = base[k0 * CC + i];
    __syncthreads();
    float acc[16];
#pragma unroll
    for (int m = 0; m < 16; ++m) acc[m] = 0.f;
    for (int j = 0; j < CC; ++j) {
        float wv = pwT[j * CC + t];
#pragma unroll
        for (int m = 0; m < 16; ++m) acc[m] += bs[m][j] * wv;
    }
    float bias = pb[t];
#pragma unroll
    for (int m = 0; m < 16; ++m) {
        float v = acc[m] + bias;
        int o = (k0 + m) * CC + t;
        emb[o] = v;
        ushort h, l;
        split2(64.f * v, h, l);
        eh[o] = h; el[o] = l;
        float sq = v * v;
#pragma unroll
        for (int d = 1; d < 64; d <<= 1) sq += __shfl_xor(sq, d);
        if (lane == 0) wpart[m][w] = sq;
    }
    __syncthreads();
    if (t < 16) esq[k0 + t] = wpart[t][0] + wpart[t][1] + wpart[t][2] + wpart[t][3];
}

// ---------------------------------------------------------------------------
// exact f32 distance+argmin for small scales (R <= 512), with fused pooling.
__global__ __launch_bounds__(256, 4) void dist_small(
    const float* __restrict__ src, const float* __restrict__ emb,
    const float* __restrict__ esq, int R, int g16, int pn, float inv,
    float* __restrict__ pval, int* __restrict__ pidx) {
    __shared__ float qs[32][CC];
    __shared__ float es[64][33];
    int t = threadIdx.x;
    int ws = t >> 6, j = t & 63;
    int k0 = blockIdx.x * 64;
    int r0c = blockIdx.y * 32;
    {
        int row = t >> 3;
        int f4b = (t & 7) * 8;
        int gr = r0c + row;
        float4 a4[8];
#pragma unroll
        for (int ii = 0; ii < 8; ++ii) a4[ii] = make_float4(0.f, 0.f, 0.f, 0.f);
        if (gr < R) {
            int b = gr / pn, p = gr - b * pn;
            const float4* sp = (const float4*)(src + ((size_t)b * 64 + (size_t)p * g16) * CC) + f4b;
            for (int i = 0; i < g16; ++i) {
#pragma unroll
                for (int ii = 0; ii < 8; ++ii) {
                    float4 v = sp[ii];
                    a4[ii].x += v.x; a4[ii].y += v.y; a4[ii].z += v.z; a4[ii].w += v.w;
                }
                sp += 64;
            }
        }
#pragma unroll
        for (int ii = 0; ii < 8; ++ii) {
            a4[ii].x *= inv; a4[ii].y *= inv; a4[ii].z *= inv; a4[ii].w *= inv;
            *(float4*)&qs[row][(f4b + ii) * 4] = a4[ii];
        }
    }
    float acc[8];
#pragma unroll
    for (int ri = 0; ri < 8; ++ri) acc[ri] = 0.f;
    for (int ck = 0; ck < 8; ++ck) {
        __syncthreads();
        {
            int code = t >> 2, cb = (t & 3) * 8;
            float4 v0 = *(const float4*)&emb[(size_t)(k0 + code) * CC + ck * 32 + cb];
            float4 v1 = *(const float4*)&emb[(size_t)(k0 + code) * CC + ck * 32 + cb + 4];
            es[code][cb + 0] = v0.x; es[code][cb + 1] = v0.y;
            es[code][cb + 2] = v0.z; es[code][cb + 3] = v0.w;
            es[code][cb + 4] = v1.x; es[code][cb + 5] = v1.y;
            es[code][cb + 6] = v1.z; es[code][cb + 7] = v1.w;
        }
        __syncthreads();
        for (int c = 0; c < 32; ++c) {
            float ev = es[j][c];
#pragma unroll
            for (int ri = 0; ri < 8; ++ri)
                acc[ri] += qs[ws + 4 * ri][ck * 32 + c] * ev;
        }
    }
    float esv = esq[k0 + j];
#pragma unroll
    for (int ri = 0; ri < 8; ++ri) {
        int r = r0c + ws + 4 * ri;
        if (r >= R) continue;
        float v = esv - 2.f * acc[ri];
        int bi = k0 + j;
#pragma unroll
        for (int d = 1; d < 64; d <<= 1) {
            float ov = __shfl_xor(v, d);
            int oi = __shfl_xor(bi, d);
            if (ov < v || (ov == v && oi < bi)) { v = ov; bi = oi; }
        }
        if (j == 0) {
            pval[(size_t)r * 64 + blockIdx.x] = v;
            pidx[(size_t)r * 64 + blockIdx.x] = bi;
        }
    }
}

// ---------------------------------------------------------------------------
// MFMA distance, pn >= 128. f16 2-split, 3 passes (hh,hl,lh), tile 128x128.
// PIPELINED: BK=32 chunks, double-buffered LDS (2x32KB); stage(ck+1) issued
// BEFORE compute(ck), ONE __syncthreads per chunk -> load latency hides under
// MFMA (T3-lite). Accumulation order identical to round 7 (hh,hl,lh per
// ascending 32-col window).
__global__ __launch_bounds__(256, 2) void dist_mfma(
    const ushort* __restrict__ qh, const ushort* __restrict__ ql,
    const ushort* __restrict__ eh, const ushort* __restrict__ el,
    const float* __restrict__ esq,
    float* __restrict__ pval, int* __restrict__ pidx) {
    // per buffer (2048 slots x 16B = 32 KB):
    //   A: slot = split*512 + row*4 + (sr ^ (row&3)),  row 0..127, 32 cols
    //   B: slot = 1024 + split*512 + kcol*4 + (sr ^ (kcol&3))
    __shared__ ushort tiles[2][2048 * 8];
    __shared__ float wv[2][128];
    __shared__ int wi[2][128];
    int t = threadIdx.x;
    int w = t >> 6, lane = t & 63;
    int l15 = lane & 15, hi = lane >> 4;
    int wr = w >> 1, wc = w & 1;
    int r0 = blockIdx.x * 128;
    int kb = blockIdx.y;
    int k0 = kb * 128;

    auto stage = [&](int ck, int bb) {
#pragma unroll
        for (int it = 0; it < 8; ++it) {
            int s = it * 256 + t;
            const ushort* g;
            if (s < 1024) {
                int a = s >> 9;
                int rem = s & 511;
                int row = rem >> 2, sr = rem & 3;
                int c = (ck << 5) + ((sr ^ (row & 3)) << 3);
                g = (a ? ql : qh) + (size_t)(r0 + row) * CC + c;
            } else {
                int s2 = s - 1024;
                int b2 = s2 >> 9;
                int rem = s2 & 511;
                int kcol = rem >> 2, sr = rem & 3;
                int c = (ck << 5) + ((sr ^ (kcol & 3)) << 3);
                g = (b2 ? el : eh) + (size_t)(k0 + kcol) * CC + c;
            }
            ushort* lb = &tiles[bb][(size_t)(it * 256 + (w << 6)) * 8];
            __builtin_amdgcn_global_load_lds(
                (const __attribute__((address_space(1))) unsigned int*)g,
                (__attribute__((address_space(3))) unsigned int*)lb, 16, 0, 0);
        }
    };

    f32x4 acc[4][4];
#pragma unroll
    for (int mi = 0; mi < 4; ++mi)
#pragma unroll
        for (int ni = 0; ni < 4; ++ni) acc[mi][ni] = (f32x4){0.f, 0.f, 0.f, 0.f};

    stage(0, 0);
    __syncthreads();  // drain prologue loads

    for (int ck = 0; ck < 8; ++ck) {
        int cur = ck & 1;
        if (ck + 1 < 8) stage(ck + 1, cur ^ 1);  // issue next-chunk loads first
        // ---- compute chunk ck from tiles[cur]
        int cs = hi;  // 16B-slot column (0..3) within the 32-col chunk
        half8 bf0[4], bf1[4], af[4];
#pragma unroll
        for (int ni = 0; ni < 4; ++ni) {
            int kcol = (wc << 6) + (ni << 4) + l15;
            int sb = 1024 + (kcol << 2) + (cs ^ (kcol & 3));
            bf0[ni] = *(const half8*)&tiles[cur][sb * 8];
            bf1[ni] = *(const half8*)&tiles[cur][(sb + 512) * 8];
        }
#pragma unroll
        for (int mi = 0; mi < 4; ++mi) {
            int row = (wr << 6) + (mi << 4) + l15;
            af[mi] = *(const half8*)&tiles[cur][((row << 2) + (cs ^ (row & 3))) * 8];
        }
#pragma unroll
        for (int mi = 0; mi < 4; ++mi)
#pragma unroll
            for (int ni = 0; ni < 4; ++ni)
                acc[mi][ni] = __builtin_amdgcn_mfma_f32_16x16x32_f16(af[mi], bf0[ni], acc[mi][ni], 0, 0, 0);
#pragma unroll
        for (int mi = 0; mi < 4; ++mi)
#pragma unroll
            for (int ni = 0; ni < 4; ++ni)
                acc[mi][ni] = __builtin_amdgcn_mfma_f32_16x16x32_f16(af[mi], bf1[ni], acc[mi][ni], 0, 0, 0);
#pragma unroll
        for (int mi = 0; mi < 4; ++mi) {
            int row = (wr << 6) + (mi << 4) + l15;
            af[mi] = *(const half8*)&tiles[cur][(512 + (row << 2) + (cs ^ (row & 3))) * 8];
        }
#pragma unroll
        for (int mi = 0; mi < 4; ++mi)
#pragma unroll
            for (int ni = 0; ni < 4; ++ni)
                acc[mi][ni] = __builtin_amdgcn_mfma_f32_16x16x32_f16(af[mi], bf0[ni], acc[mi][ni], 0, 0, 0);
        __syncthreads();  // next-chunk loads landed; buf[cur] free for ck+2
    }

    // epilogue: score = 4096*esq - 2*dot(64q,64e); per-row lexicographic argmin
    int cbase = k0 + (wc << 6) + l15;
    float es4[4];
#pragma unroll
    for (int ni = 0; ni < 4; ++ni) es4[ni] = 4096.f * esq[cbase + ni * 16];
#pragma unroll
    for (int mi = 0; mi < 4; ++mi) {
#pragma unroll
        for (int reg = 0; reg < 4; ++reg) {
            float v = es4[0] - 2.f * acc[mi][0][reg];
            int i = cbase;
#pragma unroll
            for (int ni = 1; ni < 4; ++ni) {
                float v1 = es4[ni] - 2.f * acc[mi][ni][reg];
                if (v1 < v) { v = v1; i = cbase + ni * 16; }
            }
#pragma unroll
            for (int d = 1; d < 16; d <<= 1) {
                float ov = __shfl_xor(v, d);
                int oi = __shfl_xor(i, d);
                if (ov < v || (ov == v && oi < i)) { v = ov; i = oi; }
            }
            if (l15 == 0) {
                int row = (wr << 6) + (mi << 4) + (hi << 2) + reg;
                wv[wc][row] = v;
                wi[wc][row] = i;
            }
        }
    }
    __syncthreads();
    if (t < 128) {
        float v = wv[0][t];
        int i = wi[0][t];
        float ov = wv[1][t];
        int oi = wi[1][t];
        if (ov < v || (ov == v && oi < i)) { v = ov; i = oi; }
        pval[(size_t)(r0 + t) * 64 + kb] = v;
        pidx[(size_t)(r0 + t) * 64 + kb] = i;
    }
}

// ---------------------------------------------------------------------------
// fused: per-row argmin combine + gather + interp + residual update (float4) +
// loss partial + NEXT-scale pooling (bit-identical scalar order via LDS).
__global__ __launch_bounds__(256) void update_pool(
    const float* __restrict__ emb, const float* __restrict__ pval,
    const int* __restrict__ pidx, const float* __restrict__ rin,
    float* __restrict__ rout, const float* __restrict__ f,
    float* __restrict__ outp, float* __restrict__ parts,
    ushort* __restrict__ qh, ushort* __restrict__ ql,
    float* __restrict__ qf, float* __restrict__ p16u,
    int pn, int gn, int pnn, int ks, int finalflag) {
    int blk = blockIdx.x;
    int b = blk >> 6, n16 = blk & 63;
    int t = threadIdx.x;
    int w = t >> 6, lane = t & 63;
    int n0 = n16 * 16;
    const float scale = (float)pn * (1.0f / 1024.0f);
    float s_lo = (n0 + 0.5f) * scale - 0.5f;
    if (s_lo < 0.f) s_lo = 0.f;
    int r_lo = (int)s_lo;
    float s_hi = (n0 + 15.5f) * scale - 0.5f;
    if (s_hi < 0.f) s_hi = 0.f;
    int r_hi = min((int)s_hi + 1, pn - 1);
    int cnt = r_hi - r_lo + 1;  // <= 18
    __shared__ int sidx[20];
    for (int ri = w; ri < cnt; ri += 4) {
        size_t rowg = (size_t)(b * pn + r_lo + ri) * 64;
        float v = (lane < ks) ? pval[rowg + lane] : FLT_MAX;
        int i = (lane < ks) ? pidx[rowg + lane] : 0x7fffffff;
#pragma unroll
        for (int d = 1; d < 64; d <<= 1) {
            float ov = __shfl_xor(v, d);
            int oi = __shfl_xor(i, d);
            if (ov < v || (ov == v && oi < i)) { v = ov; i = oi; }
        }
        if (lane == 0) sidx[ri] = i;
    }
    __syncthreads();
    __shared__ float4 rlds[16][64];  // 16 KB
    __shared__ float wred[4];
    int nsub = t >> 6;
    int c4 = t & 63;
    float sq = 0.f;
#pragma unroll
    for (int jj = 0; jj < 4; ++jj) {
        int j = nsub + 4 * jj;
        int n = n0 + j;
        float s = (n + 0.5f) * scale - 0.5f;
        if (s < 0.f) s = 0.f;
        int i0 = (int)s;
        float wgt = s - (float)i0;
        int i1 = min(i0 + 1, pn - 1);
        int k0 = sidx[i0 - r_lo];
        int k1 = sidx[i1 - r_lo];
        float4 e0 = ((const float4*)(emb + (size_t)k0 * CC))[c4];
        float4 e1 = ((const float4*)(emb + (size_t)k1 * CC))[c4];
        float wm = 1.f - wgt;
        float4 h = make_float4(wm * e0.x + wgt * e1.x, wm * e0.y + wgt * e1.y,
                               wm * e0.z + wgt * e1.z, wm * e0.w + wgt * e1.w);
        size_t o4 = ((size_t)b * NN + n) * 64 + c4;
        float4 rv0 = ((const float4*)rin)[o4];
        float4 rv = make_float4(rv0.x - h.x, rv0.y - h.y, rv0.z - h.z, rv0.w - h.w);
        if (!finalflag) {
            ((float4*)rout)[o4] = rv;
        } else {
            float4 fv = ((const float4*)f)[o4];
            ((float4*)outp)[o4] = make_float4(fv.x - rv.x, fv.y - rv.y,
                                              fv.z - rv.z, fv.w - rv.w);
        }
        sq += rv.x * rv.x + rv.y * rv.y + rv.z * rv.z + rv.w * rv.w;
        rlds[j][c4] = rv;
    }
    for (int off = 32; off > 0; off >>= 1) sq += __shfl_down(sq, off);
    if (lane == 0) wred[w] = sq;
    __syncthreads();
    if (t == 0) parts[blk] = wred[0] + wred[1] + wred[2] + wred[3];
    if (gn == 0) return;
    const float* rl = (const float*)rlds;  // [16][256]
    if (gn < 16) {
        float pr = 0.f;
        for (int j = 0; j < 16; ++j) {
            pr += rl[j * CC + t];
            if ((j & (gn - 1)) == (gn - 1)) {
                float mean = pr * (1.f / (float)gn);
                ushort H, L;
                split2(64.f * mean, H, L);
                size_t r = (size_t)b * pnn + (size_t)((n0 + j) / gn);
                qh[r * CC + t] = H;
                ql[r * CC + t] = L;
                pr = 0.f;
            }
        }
    } else {
        float pr = 0.f;
        for (int j = 0; j < 16; ++j) pr += rl[j * CC + t];
        if (gn == 16) qf[(size_t)blk * CC + t] = pr * (1.f / 16.f);
        else p16u[(size_t)blk * CC + t] = pr;
    }
}

// ---------------------------------------------------------------------------
__global__ void reduce_final(const float* __restrict__ parts, float* __restrict__ out) {
    __shared__ float red[256];
    int t = threadIdx.x;
    float s = 0.f;
    for (int i = t; i < SN * 512; i += 256) s += parts[i];
    red[t] = s;
    __syncthreads();
    for (int k = 128; k > 0; k >>= 1) {
        if (t < k) red[t] += red[t + k];
        __syncthreads();
    }
    if (t == 0) {
        float mean_sum = red[0] / (float)BNC;
        out[BNC] = 0.25f * mean_sum / (float)SN;
        out[BNC + 1] = mean_sum / (float)SN;
    }
}

// ---------------------------------------------------------------------------
extern "C" void kernel_launch(void* const* d_in, const int* in_sizes, int n_in,
                              void* d_out, int out_size, void* d_ws, size_t ws_size,
                              hipStream_t stream) {
    const float* f    = (const float*)d_in[0];
    const float* base = (const float*)d_in[1];
    const float* pw   = (const float*)d_in[2];
    const float* pb   = (const float*)d_in[3];
    float* out = (float*)d_out;

    float* emb   = (float*)d_ws;                    // K*C
    float* esq   = emb + (size_t)KK * CC;           // K
    float* pwT   = esq + KK;                        // C*C
    float* parts = pwT + (size_t)CC * CC;           // SN*512
    float* pval  = parts + (size_t)SN * 512;        // RMAX*64
    float* p16   = pval + (size_t)RMAX * 64;        // B*64*C
    float* p16u  = p16 + (size_t)BB * 64 * CC;      // B*64*C
    float* qf    = p16u + (size_t)BB * 64 * CC;     // 512*C
    float* resid = qf + (size_t)512 * CC;           // BNC
    int*   pidx  = (int*)(resid + BNC);             // RMAX*64
    ushort* eh = (ushort*)(pidx + (size_t)RMAX * 64);  // K*C
    ushort* el = eh + (size_t)KK * CC;              // K*C
    ushort* qh = el + (size_t)KK * CC;              // RMAX*C
    ushort* ql = qh + (size_t)RMAX * CC;            // RMAX*C

    prep_kernel<<<768, 256, 0, stream>>>(pw, pwT, f, p16);
    embed_kernel<<<KK / 16, 256, 0, stream>>>(base, pwT, pb, emb, eh, el, esq);

    for (int sidx = 0; sidx < SN; ++sidx) {
        int pn = 1 << sidx;
        int R = BB * pn;
        int ks;
        if (pn <= 64) {
            const float* src;
            float inv;
            int g16;
            if (pn == 64)      { src = qf;   g16 = 1;       inv = 1.f; }
            else if (pn == 1)  { src = p16;  g16 = 64;      inv = 1.f / 1024.f; }
            else               { src = p16u; g16 = 64 / pn; inv = 1.f / (16.f * (64 / pn)); }
            dim3 grid(64, (R + 31) / 32);
            dist_small<<<grid, 256, 0, stream>>>(src, emb, esq, R, g16, pn, inv, pval, pidx);
            ks = 64;
        } else {
            dist_mfma<<<dim3(R / 128, 32), 256, 0, stream>>>(qh, ql, eh, el, esq, pval, pidx);
            ks = 32;
        }
        int pnn = (sidx < SN - 1) ? (pn << 1) : 0;
        int gn = pnn ? (NN / pnn) : 0;
        const float* rin = (sidx == 0) ? f : resid;
        update_pool<<<BB * 64, 256, 0, stream>>>(emb, pval, pidx, rin, resid, f, out,
                                                 parts + (size_t)sidx * 512,
                                                 qh, ql, qf, p16u, pn, gn, pnn, ks,
                                                 (sidx == SN - 1) ? 1 : 0);
    }
    reduce_final<<<1, 256, 0, stream>>>(parts, out);
}

// Round 12
// 550.557 us; speedup vs baseline: 2.7698x; 1.4104x over previous
//
#include <hip/hip_runtime.h>
#include <cfloat>

#define BB 8
#define NN 1024
#define CC 256
#define KK 4096
#define SN 11
#define BNC (BB*NN*CC)
#define RMAX 8192

typedef __attribute__((ext_vector_type(8))) _Float16 half8;
typedef __attribute__((ext_vector_type(4))) float f32x4;

__device__ __forceinline__ void split2(float v, ushort& h, ushort& l) {
    union { _Float16 f; ushort u; } a, b;
    a.f = (_Float16)v;
    b.f = (_Float16)(v - (float)a.f);
    h = a.u; l = b.u;
}

// ---------------------------------------------------------------------------
// merged: blocks 0-255 embed (reads pw transposed directly; L1-resident
// 4KB/wave window); blocks 256-767 init_pool16.
__global__ __launch_bounds__(256) void embed_prep(
    const float* __restrict__ base, const float* __restrict__ pw,
    const float* __restrict__ pb, const float* __restrict__ f,
    float* __restrict__ emb, ushort* __restrict__ eh, ushort* __restrict__ el,
    float* __restrict__ esq, float* __restrict__ p16) {
    int blk = blockIdx.x;
    int t = threadIdx.x;
    if (blk >= 256) {
        int bb = blk - 256;
        int c4 = t & 63;
        const float4* src = (const float4*)(f + (size_t)bb * 16 * CC) + c4;
        float4 s = make_float4(0.f, 0.f, 0.f, 0.f);
#pragma unroll
        for (int j = 0; j < 16; ++j) {
            float4 v = src[(size_t)j * 64];
            s.x += v.x; s.y += v.y; s.z += v.z; s.w += v.w;
        }
        ((float4*)(p16 + (size_t)bb * CC))[c4] = s;
        return;
    }
    __shared__ float bs[16][CC];
    __shared__ float wpart[16][4];
    int k0 = blk * 16;
    int w = t >> 6, lane = t & 63;
    for (int i = t; i < 16 * CC; i += 256) bs[i >> 8][i & 255] = base[k0 * CC + i];
    __syncthreads();
    float acc[16];
#pragma unroll
    for (int m = 0; m < 16; ++m) acc[m] = 0.f;
    for (int j = 0; j < CC; ++j) {
        float wv = pw[t * CC + j];  // == pwT[j*CC+t]: identical values & order
#pragma unroll
        for (int m = 0; m < 16; ++m) acc[m] += bs[m][j] * wv;
    }
    float bias = pb[t];
#pragma unroll
    for (int m = 0; m < 16; ++m) {
        float v = acc[m] + bias;
        int o = (k0 + m) * CC + t;
        emb[o] = v;
        ushort h, l;
        split2(64.f * v, h, l);
        eh[o] = h; el[o] = l;
        float sq = v * v;
#pragma unroll
        for (int d = 1; d < 64; d <<= 1) sq += __shfl_xor(sq, d);
        if (lane == 0) wpart[m][w] = sq;
    }
    __syncthreads();
    if (t < 16) esq[k0 + t] = wpart[t][0] + wpart[t][1] + wpart[t][2] + wpart[t][3];
}

// ---------------------------------------------------------------------------
// exact f32 distance+argmin for small scales (R <= 512), with fused pooling.
__global__ __launch_bounds__(256, 4) void dist_small(
    const float* __restrict__ src, const float* __restrict__ emb,
    const float* __restrict__ esq, int R, int g16, int pn, float inv,
    float* __restrict__ pval, int* __restrict__ pidx) {
    __shared__ float qs[32][CC];
    __shared__ float es[64][33];
    int t = threadIdx.x;
    int ws = t >> 6, j = t & 63;
    int k0 = blockIdx.x * 64;
    int r0c = blockIdx.y * 32;
    {
        int row = t >> 3;
        int f4b = (t & 7) * 8;
        int gr = r0c + row;
        float4 a4[8];
#pragma unroll
        for (int ii = 0; ii < 8; ++ii) a4[ii] = make_float4(0.f, 0.f, 0.f, 0.f);
        if (gr < R) {
            int b = gr / pn, p = gr - b * pn;
            const float4* sp = (const float4*)(src + ((size_t)b * 64 + (size_t)p * g16) * CC) + f4b;
            for (int i = 0; i < g16; ++i) {
#pragma unroll
                for (int ii = 0; ii < 8; ++ii) {
                    float4 v = sp[ii];
                    a4[ii].x += v.x; a4[ii].y += v.y; a4[ii].z += v.z; a4[ii].w += v.w;
                }
                sp += 64;
            }
        }
#pragma unroll
        for (int ii = 0; ii < 8; ++ii) {
            a4[ii].x *= inv; a4[ii].y *= inv; a4[ii].z *= inv; a4[ii].w *= inv;
            *(float4*)&qs[row][(f4b + ii) * 4] = a4[ii];
        }
    }
    float acc[8];
#pragma unroll
    for (int ri = 0; ri < 8; ++ri) acc[ri] = 0.f;
    for (int ck = 0; ck < 8; ++ck) {
        __syncthreads();
        {
            int code = t >> 2, cb = (t & 3) * 8;
            float4 v0 = *(const float4*)&emb[(size_t)(k0 + code) * CC + ck * 32 + cb];
            float4 v1 = *(const float4*)&emb[(size_t)(k0 + code) * CC + ck * 32 + cb + 4];
            es[code][cb + 0] = v0.x; es[code][cb + 1] = v0.y;
            es[code][cb + 2] = v0.z; es[code][cb + 3] = v0.w;
            es[code][cb + 4] = v1.x; es[code][cb + 5] = v1.y;
            es[code][cb + 6] = v1.z; es[code][cb + 7] = v1.w;
        }
        __syncthreads();
        for (int c = 0; c < 32; ++c) {
            float ev = es[j][c];
#pragma unroll
            for (int ri = 0; ri < 8; ++ri)
                acc[ri] += qs[ws + 4 * ri][ck * 32 + c] * ev;
        }
    }
    float esv = esq[k0 + j];
#pragma unroll
    for (int ri = 0; ri < 8; ++ri) {
        int r = r0c + ws + 4 * ri;
        if (r >= R) continue;
        float v = esv - 2.f * acc[ri];
        int bi = k0 + j;
#pragma unroll
        for (int d = 1; d < 64; d <<= 1) {
            float ov = __shfl_xor(v, d);
            int oi = __shfl_xor(bi, d);
            if (ov < v || (ov == v && oi < bi)) { v = ov; bi = oi; }
        }
        if (j == 0) {
            pval[(size_t)r * 64 + blockIdx.x] = v;
            pidx[(size_t)r * 64 + blockIdx.x] = bi;
        }
    }
}

// ---------------------------------------------------------------------------
// MFMA distance, pn >= 128 (round-7 proven version, 687 TF = 2-phase ceiling).
// f16 2-split, 3 passes; 4 waves 2x2; wave tile 64x64; block 128x128; BK=64
// single-buffer LDS staged via global_load_lds with XOR-(row&7) pre-swizzled
// global source (free 2-way conflicts).
__global__ __launch_bounds__(256, 2) void dist_mfma(
    const ushort* __restrict__ qh, const ushort* __restrict__ ql,
    const ushort* __restrict__ eh, const ushort* __restrict__ el,
    const float* __restrict__ esq,
    float* __restrict__ pval, int* __restrict__ pidx) {
    __shared__ ushort tiles[4096 * 8];  // 64 KB
    __shared__ float wv[2][128];
    __shared__ int wi[2][128];
    int t = threadIdx.x;
    int w = t >> 6, lane = t & 63;
    int l15 = lane & 15, hi = lane >> 4;
    int wr = w >> 1, wc = w & 1;
    int r0 = blockIdx.x * 128;
    int kb = blockIdx.y;
    int k0 = kb * 128;

    f32x4 acc[4][4];
#pragma unroll
    for (int mi = 0; mi < 4; ++mi)
#pragma unroll
        for (int ni = 0; ni < 4; ++ni) acc[mi][ni] = (f32x4){0.f, 0.f, 0.f, 0.f};

    for (int ck = 0; ck < 4; ++ck) {
        __syncthreads();
#pragma unroll
        for (int it = 0; it < 16; ++it) {
            int s = it * 256 + t;
            const ushort* g;
            if (s < 2048) {
                int a = s >> 10;
                int rem = s & 1023;
                int row = rem >> 3, sr = rem & 7;
                int c = (ck << 6) + ((sr ^ (row & 7)) << 3);
                g = (a ? ql : qh) + (size_t)(r0 + row) * CC + c;
            } else {
                int s2 = s - 2048;
                int b = s2 >> 10;
                int rem = s2 & 1023;
                int kcol = rem >> 3, sr = rem & 7;
                int c = (ck << 6) + ((sr ^ (kcol & 7)) << 3);
                g = (b ? el : eh) + (size_t)(k0 + kcol) * CC + c;
            }
            ushort* lb = &tiles[(size_t)(it * 256 + (w << 6)) * 8];
            __builtin_amdgcn_global_load_lds(
                (const __attribute__((address_space(1))) unsigned int*)g,
                (__attribute__((address_space(3))) unsigned int*)lb, 16, 0, 0);
        }
        __syncthreads();

#pragma unroll
        for (int kk = 0; kk < 2; ++kk) {
            int cs = (kk << 2) + hi;
            half8 bf0[4], bf1[4], af[4];
#pragma unroll
            for (int ni = 0; ni < 4; ++ni) {
                int kcol = (wc << 6) + (ni << 4) + l15;
                int sb = 2048 + (kcol << 3) + (cs ^ (kcol & 7));
                bf0[ni] = *(const half8*)&tiles[sb * 8];
                bf1[ni] = *(const half8*)&tiles[(sb + 1024) * 8];
            }
#pragma unroll
            for (int mi = 0; mi < 4; ++mi) {
                int row = (wr << 6) + (mi << 4) + l15;
                af[mi] = *(const half8*)&tiles[((row << 3) + (cs ^ (row & 7))) * 8];
            }
#pragma unroll
            for (int mi = 0; mi < 4; ++mi)
#pragma unroll
                for (int ni = 0; ni < 4; ++ni)
                    acc[mi][ni] = __builtin_amdgcn_mfma_f32_16x16x32_f16(af[mi], bf0[ni], acc[mi][ni], 0, 0, 0);
#pragma unroll
            for (int mi = 0; mi < 4; ++mi)
#pragma unroll
                for (int ni = 0; ni < 4; ++ni)
                    acc[mi][ni] = __builtin_amdgcn_mfma_f32_16x16x32_f16(af[mi], bf1[ni], acc[mi][ni], 0, 0, 0);
#pragma unroll
            for (int mi = 0; mi < 4; ++mi) {
                int row = (wr << 6) + (mi << 4) + l15;
                af[mi] = *(const half8*)&tiles[(1024 + (row << 3) + (cs ^ (row & 7))) * 8];
            }
#pragma unroll
            for (int mi = 0; mi < 4; ++mi)
#pragma unroll
                for (int ni = 0; ni < 4; ++ni)
                    acc[mi][ni] = __builtin_amdgcn_mfma_f32_16x16x32_f16(af[mi], bf0[ni], acc[mi][ni], 0, 0, 0);
        }
    }

    int cbase = k0 + (wc << 6) + l15;
    float es4[4];
#pragma unroll
    for (int ni = 0; ni < 4; ++ni) es4[ni] = 4096.f * esq[cbase + ni * 16];
#pragma unroll
    for (int mi = 0; mi < 4; ++mi) {
#pragma unroll
        for (int reg = 0; reg < 4; ++reg) {
            float v = es4[0] - 2.f * acc[mi][0][reg];
            int i = cbase;
#pragma unroll
            for (int ni = 1; ni < 4; ++ni) {
                float v1 = es4[ni] - 2.f * acc[mi][ni][reg];
                if (v1 < v) { v = v1; i = cbase + ni * 16; }
            }
#pragma unroll
            for (int d = 1; d < 16; d <<= 1) {
                float ov = __shfl_xor(v, d);
                int oi = __shfl_xor(i, d);
                if (ov < v || (ov == v && oi < i)) { v = ov; i = oi; }
            }
            if (l15 == 0) {
                int row = (wr << 6) + (mi << 4) + (hi << 2) + reg;
                wv[wc][row] = v;
                wi[wc][row] = i;
            }
        }
    }
    __syncthreads();
    if (t < 128) {
        float v = wv[0][t];
        int i = wi[0][t];
        float ov = wv[1][t];
        int oi = wi[1][t];
        if (ov < v || (ov == v && oi < i)) { v = ov; i = oi; }
        pval[(size_t)(r0 + t) * 64 + kb] = v;
        pidx[(size_t)(r0 + t) * 64 + kb] = i;
    }
}

// ---------------------------------------------------------------------------
// fused: per-row argmin combine + gather + interp + residual update (float4) +
// loss partial + NEXT-scale pooling (bit-identical scalar order via LDS).
__global__ __launch_bounds__(256) void update_pool(
    const float* __restrict__ emb, const float* __restrict__ pval,
    const int* __restrict__ pidx, const float* __restrict__ rin,
    float* __restrict__ rout, const float* __restrict__ f,
    float* __restrict__ outp, float* __restrict__ parts,
    ushort* __restrict__ qh, ushort* __restrict__ ql,
    float* __restrict__ qf, float* __restrict__ p16u,
    int pn, int gn, int pnn, int ks, int finalflag) {
    int blk = blockIdx.x;
    int b = blk >> 6, n16 = blk & 63;
    int t = threadIdx.x;
    int w = t >> 6, lane = t & 63;
    int n0 = n16 * 16;
    const float scale = (float)pn * (1.0f / 1024.0f);
    float s_lo = (n0 + 0.5f) * scale - 0.5f;
    if (s_lo < 0.f) s_lo = 0.f;
    int r_lo = (int)s_lo;
    float s_hi = (n0 + 15.5f) * scale - 0.5f;
    if (s_hi < 0.f) s_hi = 0.f;
    int r_hi = min((int)s_hi + 1, pn - 1);
    int cnt = r_hi - r_lo + 1;  // <= 18
    __shared__ int sidx[20];
    for (int ri = w; ri < cnt; ri += 4) {
        size_t rowg = (size_t)(b * pn + r_lo + ri) * 64;
        float v = (lane < ks) ? pval[rowg + lane] : FLT_MAX;
        int i = (lane < ks) ? pidx[rowg + lane] : 0x7fffffff;
#pragma unroll
        for (int d = 1; d < 64; d <<= 1) {
            float ov = __shfl_xor(v, d);
            int oi = __shfl_xor(i, d);
            if (ov < v || (ov == v && oi < i)) { v = ov; i = oi; }
        }
        if (lane == 0) sidx[ri] = i;
    }
    __syncthreads();
    __shared__ float4 rlds[16][64];  // 16 KB
    __shared__ float wred[4];
    int nsub = t >> 6;
    int c4 = t & 63;
    float sq = 0.f;
#pragma unroll
    for (int jj = 0; jj < 4; ++jj) {
        int j = nsub + 4 * jj;
        int n = n0 + j;
        float s = (n + 0.5f) * scale - 0.5f;
        if (s < 0.f) s = 0.f;
        int i0 = (int)s;
        float wgt = s - (float)i0;
        int i1 = min(i0 + 1, pn - 1);
        int k0 = sidx[i0 - r_lo];
        int k1 = sidx[i1 - r_lo];
        float4 e0 = ((const float4*)(emb + (size_t)k0 * CC))[c4];
        float4 e1 = ((const float4*)(emb + (size_t)k1 * CC))[c4];
        float wm = 1.f - wgt;
        float4 h = make_float4(wm * e0.x + wgt * e1.x, wm * e0.y + wgt * e1.y,
                               wm * e0.z + wgt * e1.z, wm * e0.w + wgt * e1.w);
        size_t o4 = ((size_t)b * NN + n) * 64 + c4;
        float4 rv0 = ((const float4*)rin)[o4];
        float4 rv = make_float4(rv0.x - h.x, rv0.y - h.y, rv0.z - h.z, rv0.w - h.w);
        if (!finalflag) {
            ((float4*)rout)[o4] = rv;
        } else {
            float4 fv = ((const float4*)f)[o4];
            ((float4*)outp)[o4] = make_float4(fv.x - rv.x, fv.y - rv.y,
                                              fv.z - rv.z, fv.w - rv.w);
        }
        sq += rv.x * rv.x + rv.y * rv.y + rv.z * rv.z + rv.w * rv.w;
        rlds[j][c4] = rv;
    }
    for (int off = 32; off > 0; off >>= 1) sq += __shfl_down(sq, off);
    if (lane == 0) wred[w] = sq;
    __syncthreads();
    if (t == 0) parts[blk] = wred[0] + wred[1] + wred[2] + wred[3];
    if (gn == 0) return;
    const float* rl = (const float*)rlds;  // [16][256]
    if (gn < 16) {
        float pr = 0.f;
        for (int j = 0; j < 16; ++j) {
            pr += rl[j * CC + t];
            if ((j & (gn - 1)) == (gn - 1)) {
                float mean = pr * (1.f / (float)gn);
                ushort H, L;
                split2(64.f * mean, H, L);
                size_t r = (size_t)b * pnn + (size_t)((n0 + j) / gn);
                qh[r * CC + t] = H;
                ql[r * CC + t] = L;
                pr = 0.f;
            }
        }
    } else {
        float pr = 0.f;
        for (int j = 0; j < 16; ++j) pr += rl[j * CC + t];
        if (gn == 16) qf[(size_t)blk * CC + t] = pr * (1.f / 16.f);
        else p16u[(size_t)blk * CC + t] = pr;
    }
}

// ---------------------------------------------------------------------------
__global__ void reduce_final(const float* __restrict__ parts, float* __restrict__ out) {
    __shared__ float red[256];
    int t = threadIdx.x;
    float s = 0.f;
    for (int i = t; i < SN * 512; i += 256) s += parts[i];
    red[t] = s;
    __syncthreads();
    for (int k = 128; k > 0; k >>= 1) {
        if (t < k) red[t] += red[t + k];
        __syncthreads();
    }
    if (t == 0) {
        float mean_sum = red[0] / (float)BNC;
        out[BNC] = 0.25f * mean_sum / (float)SN;
        out[BNC + 1] = mean_sum / (float)SN;
    }
}

// ---------------------------------------------------------------------------
extern "C" void kernel_launch(void* const* d_in, const int* in_sizes, int n_in,
                              void* d_out, int out_size, void* d_ws, size_t ws_size,
                              hipStream_t stream) {
    const float* f    = (const float*)d_in[0];
    const float* base = (const float*)d_in[1];
    const float* pw   = (const float*)d_in[2];
    const float* pb   = (const float*)d_in[3];
    float* out = (float*)d_out;

    float* emb   = (float*)d_ws;                    // K*C
    float* esq   = emb + (size_t)KK * CC;           // K
    float* pwT   = esq + KK;                        // C*C (unused, kept for layout)
    float* parts = pwT + (size_t)CC * CC;           // SN*512
    float* pval  = parts + (size_t)SN * 512;        // RMAX*64
    float* p16   = pval + (size_t)RMAX * 64;        // B*64*C
    float* p16u  = p16 + (size_t)BB * 64 * CC;      // B*64*C
    float* qf    = p16u + (size_t)BB * 64 * CC;     // 512*C
    float* resid = qf + (size_t)512 * CC;           // BNC
    int*   pidx  = (int*)(resid + BNC);             // RMAX*64
    ushort* eh = (ushort*)(pidx + (size_t)RMAX * 64);  // K*C
    ushort* el = eh + (size_t)KK * CC;              // K*C
    ushort* qh = el + (size_t)KK * CC;              // RMAX*C
    ushort* ql = qh + (size_t)RMAX * CC;            // RMAX*C

    embed_prep<<<768, 256, 0, stream>>>(base, pw, pb, f, emb, eh, el, esq, p16);

    for (int sidx = 0; sidx < SN; ++sidx) {
        int pn = 1 << sidx;
        int R = BB * pn;
        int ks;
        if (pn <= 64) {
            const float* src;
            float inv;
            int g16;
            if (pn == 64)      { src = qf;   g16 = 1;       inv = 1.f; }
            else if (pn == 1)  { src = p16;  g16 = 64;      inv = 1.f / 1024.f; }
            else               { src = p16u; g16 = 64 / pn; inv = 1.f / (16.f * (64 / pn)); }
            dim3 grid(64, (R + 31) / 32);
            dist_small<<<grid, 256, 0, stream>>>(src, emb, esq, R, g16, pn, inv, pval, pidx);
            ks = 64;
        } else {
            dist_mfma<<<dim3(R / 128, 32), 256, 0, stream>>>(qh, ql, eh, el, esq, pval, pidx);
            ks = 32;
        }
        int pnn = (sidx < SN - 1) ? (pn << 1) : 0;
        int gn = pnn ? (NN / pnn) : 0;
        const float* rin = (sidx == 0) ? f : resid;
        update_pool<<<BB * 64, 256, 0, stream>>>(emb, pval, pidx, rin, resid, f, out,
                                                 parts + (size_t)sidx * 512,
                                                 qh, ql, qf, p16u, pn, gn, pnn, ks,
                                                 (sidx == SN - 1) ? 1 : 0);
    }
    reduce_final<<<1, 256, 0, stream>>>(parts, out);
}